// Round 1
// baseline (150.090 us; speedup 1.0000x reference)
//
#include <hip/hip_runtime.h>

// SepConv on sphere: fused quad-weight + DISCO(K=4, 9 taps) + depthwise mix,
// then DISCO(K=1, 4 taps) + pointwise 32->64 + bias.
// Structural fact: taps are always within a 3x3 (lat-clip, lon-wrap) window,
// so both contractions are 3x3 stencils with per-(k,h) coefficients.

#define H_    181
#define W_    360
#define CIN_  32
#define COUT_ 64
#define K_    4
#define NNZ_  9
#define NNZ1_ 4
#define HW_   (H_*W_)

// ---------------------------------------------------------------------------
// Stage 1: yq[c,h,w] = quad_w[h] * sum_k w_depth[c,k]
//                       * sum_j vals[(kH+h)*9+j] * quad_w[hi] * x[c,hi,(w+wi)%W]
// One block per (h, c). 9 stencil coefs built in LDS, 3 halo'd rows staged.
// ---------------------------------------------------------------------------
__global__ __launch_bounds__(128) void sepconv_stage1(
    const float* __restrict__ x, const float* __restrict__ quad_w,
    const float* __restrict__ vals, const int* __restrict__ hi,
    const int* __restrict__ wi, const float* __restrict__ w_depth,
    float* __restrict__ yq)
{
    const int h   = blockIdx.x;
    const int c   = blockIdx.y;
    const int tid = threadIdx.x;

    __shared__ float coef[9];
    __shared__ float rows[3][W_ + 2];

    const int r0 = (h > 0) ? h - 1 : 0;
    const int r2 = (h < H_ - 1) ? h + 1 : H_ - 1;
    const int rr[3] = { r0, h, r2 };
    const float* xc = x + c * HW_;

    // Stage 3 rows with +/-1 halo (longitude wraps).
    for (int i = tid; i < 3 * (W_ + 2); i += 128) {
        int sy  = i / (W_ + 2);
        int idx = i - sy * (W_ + 2);
        int col = idx - 1;
        if (col < 0)        col = W_ - 1;
        else if (col >= W_) col = 0;
        rows[sy][idx] = xc[rr[sy] * W_ + col];
    }

    // Threads 0..8 each own one stencil slot; scan the 36 entries (deterministic,
    // no atomics). slot_y = hi - h + 1 in [0,2] even at clipped boundaries.
    if (tid < 9) {
        float acc = 0.f;
        for (int k = 0; k < K_; ++k) {
            const float wd = w_depth[c * K_ + k];
            const int ebase = (k * H_ + h) * NNZ_;
            #pragma unroll
            for (int j = 0; j < NNZ_; ++j) {
                const int e   = ebase + j;
                const int hie = hi[e];
                const int wie = wi[e];
                const int sy  = hie - h + 1;
                const int sx  = (wie == 0) ? 1 : ((wie == 1) ? 2 : 0);
                if (sy * 3 + sx == tid) acc += vals[e] * quad_w[hie] * wd;
            }
        }
        coef[tid] = acc;
    }
    __syncthreads();

    const float c0 = coef[0], c1 = coef[1], c2 = coef[2];
    const float c3 = coef[3], c4 = coef[4], c5 = coef[5];
    const float c6 = coef[6], c7 = coef[7], c8 = coef[8];
    const float qh = quad_w[h];

    for (int w = tid; w < W_; w += 128) {
        float acc = c0 * rows[0][w] + c1 * rows[0][w + 1] + c2 * rows[0][w + 2]
                  + c3 * rows[1][w] + c4 * rows[1][w + 1] + c5 * rows[1][w + 2]
                  + c6 * rows[2][w] + c7 * rows[2][w + 1] + c8 * rows[2][w + 2];
        yq[c * HW_ + h * W_ + w] = acc * qh;
    }
}

// ---------------------------------------------------------------------------
// Stage 2+3: z[c,h,w] = sum_j vals1[h*4+j] * yq[c, hi1, (w+wi1)%W]
//            out[o,h,w] = bias[o] + sum_c w_point[o,c] * z[c,h,w]
// One thread per (h,w); z[32] kept in registers; w_point/bias are wave-uniform
// (scalar loads). Stores coalesced over w.
// ---------------------------------------------------------------------------
__global__ __launch_bounds__(192) void sepconv_stage2(
    const float* __restrict__ yq, const float* __restrict__ vals1,
    const int* __restrict__ hi1, const int* __restrict__ wi1,
    const float* __restrict__ w_point, const float* __restrict__ bias,
    float* __restrict__ out)
{
    const int h = blockIdx.y;
    const int w = blockIdx.x * 192 + threadIdx.x;
    if (w >= W_) return;

    float v[NNZ1_];
    int   base[NNZ1_];
    #pragma unroll
    for (int j = 0; j < NNZ1_; ++j) {
        const int e   = h * NNZ1_ + j;
        const int wie = wi1[e];
        int col;
        if (wie == 0)      col = w;
        else if (wie == 1) col = (w == W_ - 1) ? 0 : w + 1;
        else               col = (w == 0) ? W_ - 1 : w - 1;   // wie == W-1 (dx=-1)
        v[j]    = vals1[e];
        base[j] = hi1[e] * W_ + col;
    }

    float z[CIN_];
    #pragma unroll
    for (int c = 0; c < CIN_; ++c) {
        const float* p = yq + c * HW_;
        z[c] = v[0] * p[base[0]] + v[1] * p[base[1]]
             + v[2] * p[base[2]] + v[3] * p[base[3]];
    }

    #pragma unroll 4
    for (int o = 0; o < COUT_; ++o) {
        float acc = bias[o];
        #pragma unroll
        for (int c = 0; c < CIN_; ++c) acc += w_point[o * CIN_ + c] * z[c];
        out[(o * H_ + h) * W_ + w] = acc;
    }
}

extern "C" void kernel_launch(void* const* d_in, const int* in_sizes, int n_in,
                              void* d_out, int out_size, void* d_ws, size_t ws_size,
                              hipStream_t stream) {
    const float* x       = (const float*)d_in[0];
    const float* quad_w  = (const float*)d_in[1];
    const float* vals    = (const float*)d_in[2];
    // d_in[3] = seg (implied by entry ordering; unused)
    const int*   hi      = (const int*)d_in[4];
    const int*   wi      = (const int*)d_in[5];
    const float* w_depth = (const float*)d_in[6];
    const float* vals1   = (const float*)d_in[7];
    // d_in[8] = seg1 (unused)
    const int*   hi1     = (const int*)d_in[9];
    const int*   wi1     = (const int*)d_in[10];
    const float* w_point = (const float*)d_in[11];
    const float* bias    = (const float*)d_in[12];
    // d_in[13] = K (compile-time constant 4)

    float* yq  = (float*)d_ws;            // 32*181*360 floats = 8.34 MB
    float* out = (float*)d_out;

    sepconv_stage1<<<dim3(H_, CIN_), 128, 0, stream>>>(
        x, quad_w, vals, hi, wi, w_depth, yq);
    sepconv_stage2<<<dim3(2, H_), 192, 0, stream>>>(
        yq, vals1, hi1, wi1, w_point, bias, out);
}

// Round 2
// 129.421 us; speedup vs baseline: 1.1597x; 1.1597x over previous
//
#include <hip/hip_runtime.h>

// Fully-fused SepConv on sphere. Key algebra: both DISCO contractions are
// within 3x3 (lat-clip, lon-wrap) windows, so the whole chain
//   x -> *qw -> DISCO(K=4,9tap) -> depth-mix -> *qw -> DISCO(K=1,4tap) -> 1x1
// composes into ONE 5x5 stencil on x with per-(c,h) coefficients, followed
// by a 32->64 pointwise GEMV. One kernel, no workspace round-trip.
//
//   z[c,h,w] = sum_{e1 in seg1(h)} sum_k sum_{e in seg(k,hi1[e1])}
//              vals1[e1]*qw[hi1[e1]] * w_depth[c,k] * vals[e]*qw[hi[e]]
//              * x[c, hi[e], (w + d1 + d) mod W]
// with hi[e] in [h-2,h+2] (clipped) and d1+d in [-2,2]  ->  25 bins.
// C[c][25] = w_depth[c,:] . S[4][25], S channel-independent (144 taps).

#define H_    181
#define W_    360
#define CIN_  32
#define COUT_ 64
#define K_    4
#define NNZ_  9
#define NNZ1_ 4
#define HW_   (H_*W_)
#define NT_   (NNZ1_*K_*NNZ_)   // 144 composed taps per output row
#define WPB_  180               // w columns per block (2 blocks per row)
#define TPB_  192

__global__ __launch_bounds__(TPB_) void sepconv_fused(
    const float* __restrict__ x, const float* __restrict__ quad_w,
    const float* __restrict__ vals, const int* __restrict__ hi,
    const int* __restrict__ wi, const float* __restrict__ w_depth,
    const float* __restrict__ vals1, const int* __restrict__ hi1,
    const int* __restrict__ wi1, const float* __restrict__ w_point,
    const float* __restrict__ bias, float* __restrict__ out)
{
    const int h    = blockIdx.x;
    const int half = blockIdx.y;
    const int tid  = threadIdx.x;

    __shared__ float Tval[NT_];
    __shared__ int   Tbin[NT_];
    __shared__ float S[K_][25];      // channel-independent tap sums per (k,bin)
    __shared__ float C[CIN_][25];    // per-channel composed 5x5 coefs

    // --- Phase 1: decode the 144 composed taps (one thread each) ------------
    if (tid < NT_) {
        const int a   = tid / 36;            // which of the 4 stage-2 taps
        const int rem = tid - a * 36;
        const int k   = rem / 9;
        const int j   = rem - k * 9;
        const int e1  = h * NNZ1_ + a;
        const int m   = hi1[e1];             // middle row, in clip(h-1..h+1)
        const int w1  = wi1[e1];
        const int d1  = (w1 == 1) ? 1 : ((w1 == 0) ? 0 : -1);
        const int e   = (k * H_ + m) * NNZ_ + j;
        const int r   = hi[e];               // source row, in clip(h-2..h+2)
        const int w0  = wi[e];
        const int d   = (w0 == 1) ? 1 : ((w0 == 0) ? 0 : -1);
        Tval[tid] = vals1[e1] * quad_w[m] * vals[e] * quad_w[r];
        Tbin[tid] = (r - h + 2) * 5 + (d1 + d + 2);   // always in [0,25)
    }
    __syncthreads();

    // --- Phase 2: S[k][bin] — parallel over (k,bin), read-only LDS scans ----
    // (avoids a 144-long dependent LDS read-modify-write chain)
    if (tid < K_ * 25) {
        const int k   = tid / 25;
        const int bin = tid - k * 25;
        float s = 0.f;
        #pragma unroll
        for (int a = 0; a < NNZ1_; ++a)
            #pragma unroll
            for (int j = 0; j < NNZ_; ++j) {
                const int t2 = a * 36 + k * 9 + j;
                if (Tbin[t2] == bin) s += Tval[t2];
            }
        S[k][bin] = s;
    }
    __syncthreads();

    // --- Phase 3: C[c][bin] = w_depth[c,:] . S[:,bin] -----------------------
    for (int item = tid; item < CIN_ * 25; item += TPB_) {
        const int c   = item / 25;
        const int bin = item - c * 25;
        float acc = 0.f;
        #pragma unroll
        for (int k = 0; k < K_; ++k) acc += w_depth[c * K_ + k] * S[k][bin];
        C[c][bin] = acc;
    }
    __syncthreads();

    // --- Main: thread-per-pixel 5x5 stencil + 32->64 GEMV -------------------
    const int w = half * WPB_ + tid;
    if (tid >= WPB_ || w >= W_) return;

    int rowbase[5];
    #pragma unroll
    for (int rb = 0; rb < 5; ++rb) {
        int r = h - 2 + rb;
        r = (r < 0) ? 0 : ((r > H_ - 1) ? H_ - 1 : r);
        rowbase[rb] = r * W_;   // coef is 0 for clipped-away bins; row is valid
    }
    int col[5];
    #pragma unroll
    for (int s = 0; s < 5; ++s) {
        int cc = w - 2 + s;
        if (cc < 0)   cc += W_;
        if (cc >= W_) cc -= W_;
        col[s] = cc;
    }

    float z[CIN_];
    #pragma unroll 2
    for (int c = 0; c < CIN_; ++c) {
        const float* xc = x + c * HW_;
        float acc = 0.f;
        #pragma unroll
        for (int rb = 0; rb < 5; ++rb) {
            const float* xr = xc + rowbase[rb];
            #pragma unroll
            for (int s = 0; s < 5; ++s)
                acc += C[c][rb * 5 + s] * xr[col[s]];
        }
        z[c] = acc;
    }

    float* op = out + h * W_ + w;   // out[o][h][w], o-stride HW_
    #pragma unroll 2
    for (int o = 0; o < COUT_; ++o) {
        float acc = bias[o];
        #pragma unroll
        for (int c = 0; c < CIN_; ++c) acc += w_point[o * CIN_ + c] * z[c];
        op[o * HW_] = acc;
    }
}

extern "C" void kernel_launch(void* const* d_in, const int* in_sizes, int n_in,
                              void* d_out, int out_size, void* d_ws, size_t ws_size,
                              hipStream_t stream) {
    const float* x       = (const float*)d_in[0];
    const float* quad_w  = (const float*)d_in[1];
    const float* vals    = (const float*)d_in[2];
    // d_in[3] = seg   (implied by entry ordering; unused)
    const int*   hi      = (const int*)d_in[4];
    const int*   wi      = (const int*)d_in[5];
    const float* w_depth = (const float*)d_in[6];
    const float* vals1   = (const float*)d_in[7];
    // d_in[8] = seg1  (unused)
    const int*   hi1     = (const int*)d_in[9];
    const int*   wi1     = (const int*)d_in[10];
    const float* w_point = (const float*)d_in[11];
    const float* bias    = (const float*)d_in[12];
    // d_in[13] = K (compile-time constant 4)

    sepconv_fused<<<dim3(H_, 2), TPB_, 0, stream>>>(
        x, quad_w, vals, hi, wi, w_depth, vals1, hi1, wi1,
        w_point, bias, (float*)d_out);
}